// Round 4
// baseline (254.745 us; speedup 1.0000x reference)
//
#include <hip/hip_runtime.h>
#include <hip/hip_bf16.h>

#define N_NODES 50000
#define N_EDGES 500000
#define N_GRAPHS 64
#define FDIM 256   // H*HID
#define NHEAD 8
#define NC 10
#define SLOPE 0.2f
#define MPAD 50048  // N_NODES rounded up to 64
#define NBKT 196              // ceil(N_NODES/256) coarse buckets (dst>>8)
#define CNTN (NBKT * 256)     // 50176 = per-(bucket,block) count matrix
#define SCAN_NB (CNTN / 1024) // 49 scan blocks of 1024 (exact)
#define NB1 256               // pass-1 bucketing blocks
#define EPB 1956              // edges per pass-1 block (mult of 4; 256*1956 >= E)
#define LDSW 40               // LDS row stride in shorts: 80B -> <=2-way bank conflict
#define PSPLIT 16             // pool: slices per graph (64*16 = 1024 blocks)
#define CAST_THREADS (256*128 + 256*256 + N_NODES)   // 148304
#define CAST_NB ((CAST_THREADS + 255) / 256)         // 580

typedef __attribute__((ext_vector_type(8))) short bf16x8;
typedef __attribute__((ext_vector_type(4))) float f32x4;
typedef __attribute__((ext_vector_type(2))) float f32x2;
typedef __attribute__((ext_vector_type(4))) unsigned u32x4;

__device__ __forceinline__ unsigned short f2bf(float f) {
  unsigned x = __float_as_uint(f);
  x += 0x7fff + ((x >> 16) & 1);   // RNE
  return (unsigned short)(x >> 16);
}
__device__ __forceinline__ float b2f(unsigned short u) {
  return __uint_as_float((unsigned)u << 16);
}
// XOR swizzle for the gemm epilogue LDS stage (bijective per 256B row, keeps 16B blocks)
__device__ __forceinline__ int fswz(int node, int off) {
  return off ^ ((node & 7) << 5) ^ (((node >> 3) & 1) << 4);
}

// ---------------- fused: weight transposes + gstart + coarse dst histogram ----------------
// blocks [0,NB1): per-block LDS histogram over 196 buckets (dst>>8) -> counts
// blocks [NB1, NB1+CAST_NB): weight transposes + gstart fill + rowstart[N]=E
__global__ void cast_hist_kernel(const float* __restrict__ W1, const float* __restrict__ W2,
                                 unsigned short* __restrict__ Wt1, unsigned short* __restrict__ Wt2,
                                 const int* __restrict__ n2g, int* __restrict__ gstart,
                                 const int* __restrict__ dst, int* __restrict__ counts,
                                 int* __restrict__ rowstart) {
  int t = threadIdx.x;
  if (blockIdx.x < NB1) {
    __shared__ int hist[NBKT];
    int b = blockIdx.x;
    if (t < NBKT) hist[t] = 0;
    __syncthreads();
    int start = b * EPB;
    int end = min(start + EPB, N_EDGES);
    for (int base = start + t * 4; base < end; base += 1024) {
      if (base + 3 < end) {
        int4 d = *(const int4*)(dst + base);
        atomicAdd(&hist[d.x >> 8], 1); atomicAdd(&hist[d.y >> 8], 1);
        atomicAdd(&hist[d.z >> 8], 1); atomicAdd(&hist[d.w >> 8], 1);
      } else {
        for (int e2 = base; e2 < end; ++e2) atomicAdd(&hist[dst[e2] >> 8], 1);
      }
    }
    __syncthreads();
    if (t < NBKT) counts[t * NB1 + b] = hist[t];
    return;
  }
  int e = (blockIdx.x - NB1) * 256 + t;
  if (e == 0) rowstart[N_NODES] = N_EDGES;
  if (e < 256 * 128) {
    int n = e / 128, k = e % 128;
    Wt1[(size_t)n * 128 + k] = f2bf(W1[(size_t)k * 256 + n]);
  } else if (e < 256 * 128 + 256 * 256) {
    int t2 = e - 256 * 128;
    int n = t2 / 256, k = t2 % 256;
    Wt2[(size_t)n * 256 + k] = f2bf(W2[(size_t)k * 256 + n]);
  } else {
    int i = e - (256 * 128 + 256 * 256);
    if (i < N_NODES) {
      int g1 = n2g[i];
      int g0 = (i == 0) ? -1 : n2g[i - 1];
      for (int g = g0 + 1; g <= g1; ++g) gstart[g] = i;
      if (i == N_NODES - 1) {
        for (int g = g1 + 1; g <= N_GRAPHS; ++g) gstart[g] = N_NODES;
      }
    }
  }
}

// ---- local exclusive scan of counts[0..CNTN) -> cbase (block-local) + bsum ----
__global__ void scan_local_kernel(const int* __restrict__ deg, int* __restrict__ outv,
                                  int* __restrict__ bsum, int n) {
  __shared__ int ws[4];
  int t = threadIdx.x, lane = t & 63, w = t >> 6;
  int base = blockIdx.x * 1024 + t * 4;
  int4 v = make_int4(0, 0, 0, 0);
  if (base + 3 < n) {
    v = *(const int4*)(deg + base);
  } else {
    if (base + 0 < n) v.x = deg[base + 0];
    if (base + 1 < n) v.y = deg[base + 1];
    if (base + 2 < n) v.z = deg[base + 2];
    if (base + 3 < n) v.w = deg[base + 3];
  }
  int s = v.x + v.y + v.z + v.w;
  int x = s;
  #pragma unroll
  for (int off = 1; off < 64; off <<= 1) {
    int y = __shfl_up(x, off);
    if (lane >= off) x += y;
  }
  if (lane == 63) ws[w] = x;
  __syncthreads();
  int woff = 0;
  #pragma unroll
  for (int i = 0; i < 4; ++i) woff += (i < w) ? ws[i] : 0;
  int excl = woff + x - s;
  int4 o;
  o.x = excl;
  o.y = excl + v.x;
  o.z = excl + v.x + v.y;
  o.w = excl + v.x + v.y + v.z;
  if (base + 3 < n) {
    *(int4*)(outv + base) = o;
  } else {
    if (base + 0 < n) outv[base + 0] = o.x;
    if (base + 1 < n) outv[base + 1] = o.y;
    if (base + 2 < n) outv[base + 2] = o.z;
    if (base + 3 < n) outv[base + 3] = o.w;
  }
  if (t == 255) bsum[blockIdx.x] = woff + x;
}

// Pass 1b: rank-scatter (src,dst) into bucket-major ebuf. Absolute LDS cursors
// (local cbase + block-prefix of bsum folded in at block start — scan_add deleted).
__global__ void bucket_scatter_kernel(const int* __restrict__ src, const int* __restrict__ dst,
                                      const int* __restrict__ cbase, const int* __restrict__ bsum,
                                      int2* __restrict__ ebuf) {
  __shared__ int cur[NBKT];
  __shared__ int boffl[SCAN_NB];
  int t = threadIdx.x, b = blockIdx.x;
  if (t < 64) {
    int v = (t < SCAN_NB) ? bsum[t] : 0;
    int x = v;
    #pragma unroll
    for (int off = 1; off < 64; off <<= 1) {
      int y = __shfl_up(x, off);
      if (t >= off) x += y;
    }
    if (t < SCAN_NB) boffl[t] = x - v;
  }
  __syncthreads();
  if (t < NBKT) {
    int idx = t * NB1 + b;
    cur[t] = cbase[idx] + boffl[idx >> 10];
  }
  __syncthreads();
  int start = b * EPB;
  int end = min(start + EPB, N_EDGES);
  for (int base = start + t * 4; base < end; base += 1024) {
    if (base + 3 < end) {
      int4 s = *(const int4*)(src + base);
      int4 d = *(const int4*)(dst + base);
      int r;
      r = atomicAdd(&cur[d.x >> 8], 1); ebuf[r] = make_int2(s.x, d.x);
      r = atomicAdd(&cur[d.y >> 8], 1); ebuf[r] = make_int2(s.y, d.y);
      r = atomicAdd(&cur[d.z >> 8], 1); ebuf[r] = make_int2(s.z, d.z);
      r = atomicAdd(&cur[d.w >> 8], 1); ebuf[r] = make_int2(s.w, d.w);
    } else {
      for (int e2 = base; e2 < end; ++e2) {
        int dd = dst[e2];
        int r = atomicAdd(&cur[dd >> 8], 1);
        ebuf[r] = make_int2(src[e2], dd);
      }
    }
  }
}

// Pass 2: one block per coarse bucket -> final rowstart + esrc, all in LDS.
__global__ void csr_bucket_kernel(const int2* __restrict__ ebuf, const int* __restrict__ cbase,
                                  const int* __restrict__ bsum,
                                  int* __restrict__ rowstart, int* __restrict__ esrc) {
  __shared__ int hist[256];
  __shared__ int cur[256];
  __shared__ int ws[4];
  __shared__ int boffl[SCAN_NB];
  int t = threadIdx.x;
  int bkt = blockIdx.x;
  hist[t] = 0;
  if (t >= 64 && t < 128) {
    int tt = t - 64;
    int v = (tt < SCAN_NB) ? bsum[tt] : 0;
    int x = v;
    #pragma unroll
    for (int off = 1; off < 64; off <<= 1) {
      int y = __shfl_up(x, off);
      if (tt >= off) x += y;
    }
    if (tt < SCAN_NB) boffl[tt] = x - v;
  }
  __syncthreads();
  int i0 = bkt * NB1;
  int segstart = cbase[i0] + boffl[i0 >> 10];
  int segend = N_EDGES;
  if (bkt + 1 < NBKT) {
    int i1 = (bkt + 1) * NB1;
    segend = cbase[i1] + boffl[i1 >> 10];
  }
  for (int e = segstart + t; e < segend; e += 256)
    atomicAdd(&hist[ebuf[e].y & 255], 1);
  __syncthreads();
  int lane = t & 63, w = t >> 6;
  int v = hist[t], x = v;
  #pragma unroll
  for (int off = 1; off < 64; off <<= 1) {
    int y = __shfl_up(x, off);
    if (lane >= off) x += y;
  }
  if (lane == 63) ws[w] = x;
  __syncthreads();
  int woff = 0;
  #pragma unroll
  for (int i = 0; i < 4; ++i) woff += (i < w) ? ws[i] : 0;
  int excl = woff + x - v;
  cur[t] = excl;
  int node = bkt * 256 + t;
  if (node < N_NODES) rowstart[node] = segstart + excl;
  __syncthreads();
  for (int e = segstart + t; e < segend; e += 256) {
    int2 p = ebuf[e];
    int r = atomicAdd(&cur[p.y & 255], 1);
    esrc[segstart + r] = p.x;
  }
}

// ---------------- LDS-staged MFMA GEMM + fused attention logits ----------------
template<int K, bool AF32>
__global__ void gemm_mfma(const void* __restrict__ Avoid,
                          const unsigned short* __restrict__ Wt,
                          unsigned char* __restrict__ fs,
                          const float* __restrict__ al, const float* __restrict__ ar,
                          float* __restrict__ el, float* __restrict__ er, int nrows) {
  constexpr int KC = K / 32;
  __shared__ __align__(16) unsigned short LDSbuf[(64 + 256) * LDSW];   // 25.6 KB
  unsigned short* Albs = LDSbuf;
  unsigned short* Wlds = LDSbuf + 64 * LDSW;
  const float* Af = (const float*)Avoid;
  const unsigned short* Ab = (const unsigned short*)Avoid;
  int t = threadIdx.x;
  int lane = t & 63;
  int w = t >> 6;
  int row0 = blockIdx.x * 64;
  int m = lane & 15;
  int q = lane >> 4;
  float4 a32[2];
  bf16x8 a16;
  bf16x8 wtr[4];
  int arow = t >> 2, apiece = t & 3;
  int agrow = min(row0 + arow, nrows - 1);
  int frow0 = t >> 3, fquad0 = t & 7;
  int frow1 = (256 + t) >> 3, fquad1 = t & 7;
  int fgrow0 = min(row0 + frow0, nrows - 1);
  int fgrow1 = min(row0 + frow1, nrows - 1);

  auto stage = [&](int kc) {
    if (AF32) {
      a32[0] = *(const float4*)(Af + (size_t)fgrow0 * K + kc * 32 + fquad0 * 4);
      a32[1] = *(const float4*)(Af + (size_t)fgrow1 * K + kc * 32 + fquad1 * 4);
    } else {
      a16 = *(const bf16x8*)(Ab + (size_t)agrow * K + kc * 32 + apiece * 8);
    }
    #pragma unroll
    for (int j = 0; j < 4; ++j) {
      int row = j * 64 + (t >> 2);
      wtr[j] = *(const bf16x8*)(Wt + (size_t)row * K + kc * 32 + (t & 3) * 8);
    }
  };
  auto commit = [&]() {
    if (AF32) {
      ushort4 o0, o1;
      o0.x = f2bf(a32[0].x); o0.y = f2bf(a32[0].y); o0.z = f2bf(a32[0].z); o0.w = f2bf(a32[0].w);
      o1.x = f2bf(a32[1].x); o1.y = f2bf(a32[1].y); o1.z = f2bf(a32[1].z); o1.w = f2bf(a32[1].w);
      *(ushort4*)(Albs + frow0 * LDSW + fquad0 * 4) = o0;
      *(ushort4*)(Albs + frow1 * LDSW + fquad1 * 4) = o1;
    } else {
      *(bf16x8*)(Albs + arow * LDSW + apiece * 8) = a16;
    }
    #pragma unroll
    for (int j = 0; j < 4; ++j) {
      int row = j * 64 + (t >> 2);
      *(bf16x8*)(Wlds + row * LDSW + (t & 3) * 8) = wtr[j];
    }
  };

  f32x4 acc[16];
  #pragma unroll
  for (int nt = 0; nt < 16; ++nt) acc[nt] = (f32x4){0.f, 0.f, 0.f, 0.f};

  stage(0);
  commit();
  for (int kc = 0; kc < KC; ++kc) {
    __syncthreads();
    if (kc + 1 < KC) stage(kc + 1);
    bf16x8 af = *(const bf16x8*)(Albs + (w * 16 + m) * LDSW + q * 8);
    #pragma unroll
    for (int nt = 0; nt < 16; ++nt) {
      bf16x8 bfv = *(const bf16x8*)(Wlds + (nt * 16 + m) * LDSW + q * 8);
      acc[nt] = __builtin_amdgcn_mfma_f32_16x16x32_bf16(bfv, af, acc[nt], 0, 0, 0);
    }
    __syncthreads();
    if (kc + 1 < KC) commit();
  }
  // LDSbuf dead after the final barrier -> reuse for the coalescing epilogue.
  unsigned char* fsst = (unsigned char*)LDSbuf;          // 16384 B
  float* elst = (float*)(fsst + 16384);                  // 2048 B
  float* erst = elst + 512;                              // 2048 B

  int nloc = w * 16 + m;
  float elh[NHEAD], erh[NHEAD];
  #pragma unroll
  for (int h = 0; h < NHEAD; ++h) { elh[h] = 0.f; erh[h] = 0.f; }
  #pragma unroll
  for (int nt = 0; nt < 16; ++nt) {
    int h = nt >> 1;
    int c0 = (nt & 1) * 16 + q * 4;
    float4 a4 = *(const float4*)(al + h * 32 + c0);
    float4 r4 = *(const float4*)(ar + h * 32 + c0);
    elh[h] += acc[nt][0] * a4.x + acc[nt][1] * a4.y + acc[nt][2] * a4.z + acc[nt][3] * a4.w;
    erh[h] += acc[nt][0] * r4.x + acc[nt][1] * r4.y + acc[nt][2] * r4.z + acc[nt][3] * r4.w;
  }
  #pragma unroll
  for (int h = 0; h < NHEAD; ++h) {
    elh[h] += __shfl_xor(elh[h], 16); elh[h] += __shfl_xor(elh[h], 32);
    erh[h] += __shfl_xor(erh[h], 16); erh[h] += __shfl_xor(erh[h], 32);
  }
  #pragma unroll
  for (int nt = 0; nt < 16; ++nt) {
    int pk = 0;
    pk = __builtin_amdgcn_cvt_pk_fp8_f32(acc[nt][0], acc[nt][1], pk, false);
    pk = __builtin_amdgcn_cvt_pk_fp8_f32(acc[nt][2], acc[nt][3], pk, true);
    *(unsigned*)(fsst + nloc * 256 + fswz(nloc, nt * 16 + q * 4)) = (unsigned)pk;
  }
  *(float2*)(elst + nloc * 8 + q * 2) = make_float2(elh[2 * q], elh[2 * q + 1]);
  *(float2*)(erst + nloc * 8 + q * 2) = make_float2(erh[2 * q], erh[2 * q + 1]);
  __syncthreads();
  #pragma unroll
  for (int i = 0; i < 4; ++i) {
    int p = i * 4096 + t * 16;
    int nn = p >> 8, off = p & 255;
    u32x4 d = *(const u32x4*)(fsst + nn * 256 + fswz(nn, off));
    *(u32x4*)(fs + (size_t)row0 * 256 + p) = d;
  }
  if (t < 128) {
    *(float4*)(el + (size_t)row0 * 8 + t * 4) = *(const float4*)(elst + t * 4);
  } else {
    int tt = t - 128;
    *(float4*)(er + (size_t)row0 * 8 + tt * 4) = *(const float4*)(erst + tt * 4);
  }
}

// ---------------- fused edge softmax + aggregation ----------------
// One wave per STRIP of 4 consecutive dst nodes, 1-deep software pipeline:
// the (el-gather + 8 fs-gathers) of group g+1 / next node issue before the
// compute of group g, hiding ~600cy of gather latency under ~300cy of VALU.
// Lane roles unchanged: producer (t8=lane>>3 edge-slot, hh=lane&7 head),
// consumer (h=lane>>3 head, channels lane*4..+3). deg>64 -> cold chunk loop.
template<bool RELU>
__global__ __launch_bounds__(256, 6)
void edge_agg_kernel(const int* __restrict__ rowstart, const int* __restrict__ esrc,
                     const float* __restrict__ el, const float* __restrict__ er,
                     const unsigned char* __restrict__ fs,
                     const float* __restrict__ bias,
                     unsigned short* __restrict__ out, int nnodes) {
  int lane = threadIdx.x & 63;
  int w = threadIdx.x >> 6;
  int v0 = (blockIdx.x * 4 + w) * 4;        // strip base node (50000 = 3125*16 exact)
  if (v0 >= nnodes) return;
  int h = lane >> 3;
  int t8 = lane >> 3;
  int hh = lane & 7;
  const unsigned char* fsl = fs + lane * 4;
  const float* elp = el;
  const float4 b = *(const float4*)(bias + lane * 4);

  // strip prologue: rowstarts via one lane-indexed load + shfl
  int rsl = rowstart[min(v0 + lane, nnodes)];   // lanes 0..4 meaningful
  int rs[5];
  #pragma unroll
  for (int i = 0; i < 5; ++i) rs[i] = __shfl(rsl, i);
  int degv[4], mmx[4], es[4];
  float erw[4];
  #pragma unroll
  for (int i = 0; i < 4; ++i) {
    degv[i] = rs[i + 1] - rs[i];
    mmx[i] = min(degv[i], 64);
    erw[i] = er[(unsigned)(v0 + i) * 8u + hh];
    es[i] = 0;
    if (mmx[i] > 0) es[i] = esrc[rs[i] + min(lane, mmx[i] - 1)];
  }

  auto issue = [&](int esv, int mmv, float erv, int gbase, float& x, unsigned* f) {
    int sj = __shfl(esv, max(min(gbase + t8, mmv - 1), 0));
    x = elp[(unsigned)sj * 8u + hh] + erv;
    #pragma unroll
    for (int t = 0; t < 8; ++t) {
      int s = __shfl(esv, max(min(gbase + t, mmv - 1), 0));
      f[t] = *(const unsigned*)(fsl + ((unsigned)s << 8));
    }
  };

  float xC; unsigned fC[8];
  issue(es[0], mmx[0], erw[0], 0, xC, fC);

  #pragma unroll
  for (int i = 0; i < 4; ++i) {
    float4 acc0 = make_float4(0.f, 0.f, 0.f, 0.f);
    float4 acc1 = make_float4(0.f, 0.f, 0.f, 0.f);
    float ws0 = 0.f, ws1 = 0.f;
    int G = max((mmx[i] + 7) >> 3, 1);
    for (int g = 0; g < G; ++g) {
      bool last = (g + 1 >= G);
      float xN = 0.f; unsigned fN[8];
      #pragma unroll
      for (int t = 0; t < 8; ++t) fN[t] = 0u;
      if (!(last && i == 3)) {
        int esn = last ? es[(i < 3) ? i + 1 : 3] : es[i];
        int mmn = last ? mmx[(i < 3) ? i + 1 : 3] : mmx[i];
        float ern = last ? erw[(i < 3) ? i + 1 : 3] : erw[i];
        int gbn = last ? 0 : (g + 1) * 8;
        issue(esn, mmn, ern, gbn, xN, fN);
      }
      // compute current group
      float xl = fmaxf(xC, SLOPE * xC);
      float wp = __expf(xl);
      if (g * 8 + t8 >= mmx[i]) wp = 0.f;
      float wt[8];
      #pragma unroll
      for (int t = 0; t < 8; ++t) wt[t] = __shfl(wp, t * 8 + h);
      #pragma unroll
      for (int t = 0; t < 8; ++t) {
        float wgt = wt[t];
        f32x2 lo = __builtin_amdgcn_cvt_pk_f32_fp8(fC[t], false);
        f32x2 hi = __builtin_amdgcn_cvt_pk_f32_fp8(fC[t], true);
        if (t & 1) {
          ws1 += wgt;
          acc1.x = fmaf(wgt, lo.x, acc1.x);
          acc1.y = fmaf(wgt, lo.y, acc1.y);
          acc1.z = fmaf(wgt, hi.x, acc1.z);
          acc1.w = fmaf(wgt, hi.y, acc1.w);
        } else {
          ws0 += wgt;
          acc0.x = fmaf(wgt, lo.x, acc0.x);
          acc0.y = fmaf(wgt, lo.y, acc0.y);
          acc0.z = fmaf(wgt, hi.x, acc0.z);
          acc0.w = fmaf(wgt, hi.y, acc0.w);
        }
      }
      xC = xN;
      #pragma unroll
      for (int t = 0; t < 8; ++t) fC[t] = fN[t];
    }
    // cold path: degrees beyond the first 64 edges
    if (__builtin_expect(degv[i] > 64, 0)) {
      for (int base = 64; base < degv[i]; base += 64) {
        int mm2 = min(degv[i] - base, 64);
        int es2 = esrc[rs[i] + base + min(lane, mm2 - 1)];
        for (int j0 = 0; j0 < mm2; j0 += 8) {
          int sj = __shfl(es2, min(j0 + t8, mm2 - 1));
          float x = elp[(unsigned)sj * 8u + hh] + erw[i];
          x = fmaxf(x, SLOPE * x);
          float wp2 = __expf(x);
          if (j0 + t8 >= mm2) wp2 = 0.f;
          float wt[8]; unsigned f2[8];
          #pragma unroll
          for (int t = 0; t < 8; ++t) wt[t] = __shfl(wp2, t * 8 + h);
          #pragma unroll
          for (int t = 0; t < 8; ++t) {
            int s = __shfl(es2, min(j0 + t, mm2 - 1));
            f2[t] = *(const unsigned*)(fsl + ((unsigned)s << 8));
          }
          #pragma unroll
          for (int t = 0; t < 8; ++t) {
            float wgt = wt[t];
            f32x2 lo = __builtin_amdgcn_cvt_pk_f32_fp8(f2[t], false);
            f32x2 hi = __builtin_amdgcn_cvt_pk_f32_fp8(f2[t], true);
            if (t & 1) {
              ws1 += wgt;
              acc1.x = fmaf(wgt, lo.x, acc1.x); acc1.y = fmaf(wgt, lo.y, acc1.y);
              acc1.z = fmaf(wgt, hi.x, acc1.z); acc1.w = fmaf(wgt, hi.y, acc1.w);
            } else {
              ws0 += wgt;
              acc0.x = fmaf(wgt, lo.x, acc0.x); acc0.y = fmaf(wgt, lo.y, acc0.y);
              acc0.z = fmaf(wgt, hi.x, acc0.z); acc0.w = fmaf(wgt, hi.y, acc0.w);
            }
          }
        }
      }
    }
    // node epilogue
    float wsum = ws0 + ws1;
    float4 acc;
    acc.x = acc0.x + acc1.x; acc.y = acc0.y + acc1.y;
    acc.z = acc0.z + acc1.z; acc.w = acc0.w + acc1.w;
    float rdenom = (degv[i] > 0) ? (1.0f / wsum) : 0.f;
    acc.x = fmaf(acc.x, rdenom, b.x);
    acc.y = fmaf(acc.y, rdenom, b.y);
    acc.z = fmaf(acc.z, rdenom, b.z);
    acc.w = fmaf(acc.w, rdenom, b.w);
    if (RELU) {
      acc.x = fmaxf(acc.x, 0.f); acc.y = fmaxf(acc.y, 0.f);
      acc.z = fmaxf(acc.z, 0.f); acc.w = fmaxf(acc.w, 0.f);
    }
    ushort4 o;
    o.x = f2bf(acc.x); o.y = f2bf(acc.y); o.z = f2bf(acc.z); o.w = f2bf(acc.w);
    *(ushort4*)(out + (size_t)(v0 + i) * FDIM + lane * 4) = o;
  }
}

// ---------------- pool: split-K partials (1024 blocks), zero atomics ----------------
__global__ void pool_partial_kernel(const unsigned short* __restrict__ h2,
                                    const int* __restrict__ gstart,
                                    float* __restrict__ ppart) {
  int t = threadIdx.x;   // channel
  int g = blockIdx.x / PSPLIT;
  int s = blockIdx.x % PSPLIT;
  int n0 = gstart[g], n1 = gstart[g + 1];
  int cnt = n1 - n0;
  int chunk = (cnt + PSPLIT - 1) / PSPLIT;
  int a = n0 + s * chunk;
  int bnd = min(a + chunk, n1);
  float s0 = 0.f, s1 = 0.f, s2 = 0.f, s3 = 0.f;
  int n = a;
  for (; n + 4 <= bnd; n += 4) {
    s0 += b2f(h2[(size_t)(n + 0) * FDIM + t]);
    s1 += b2f(h2[(size_t)(n + 1) * FDIM + t]);
    s2 += b2f(h2[(size_t)(n + 2) * FDIM + t]);
    s3 += b2f(h2[(size_t)(n + 3) * FDIM + t]);
  }
  for (; n < bnd; ++n) s0 += b2f(h2[(size_t)n * FDIM + t]);
  ppart[(size_t)blockIdx.x * FDIM + t] = (s0 + s1) + (s2 + s3);
}

// ---------------- fused pool-reduce + classifier: one block per graph ----------------
__global__ void pool_cls_kernel(const float* __restrict__ ppart, const int* __restrict__ gstart,
                                const float* __restrict__ Wc, const float* __restrict__ bcv,
                                float* __restrict__ out) {
  __shared__ float hgl[FDIM];
  int t = threadIdx.x, g = blockIdx.x;
  float s = 0.f;
  #pragma unroll
  for (int sp = 0; sp < PSPLIT; ++sp)
    s += ppart[(size_t)(g * PSPLIT + sp) * FDIM + t];
  hgl[t] = s;
  __syncthreads();
  int cnt = gstart[g + 1] - gstart[g];
  float inv = (cnt > 0) ? (1.0f / (float)cnt) : 1.0f;
  int w = t >> 6, lane = t & 63;
  for (int j = w; j < NC; j += 4) {
    float p = 0.f;
    #pragma unroll
    for (int k = 0; k < 4; ++k) {
      int c = lane * 4 + k;
      p += hgl[c] * Wc[c * NC + j];
    }
    #pragma unroll
    for (int off = 1; off < 64; off <<= 1) p += __shfl_xor(p, off);
    if (lane == 0) out[g * NC + j] = p * inv + bcv[j];
  }
}

extern "C" void kernel_launch(void* const* d_in, const int* in_sizes, int n_in,
                              void* d_out, int out_size, void* d_ws, size_t ws_size,
                              hipStream_t stream) {
  const float* feat = (const float*)d_in[0];
  const int* src    = (const int*)d_in[1];
  const int* dst    = (const int*)d_in[2];
  const int* n2g    = (const int*)d_in[3];
  const float* W1  = (const float*)d_in[4];
  const float* al1 = (const float*)d_in[5];
  const float* ar1 = (const float*)d_in[6];
  const float* b1  = (const float*)d_in[7];
  const float* W2  = (const float*)d_in[8];
  const float* al2 = (const float*)d_in[9];
  const float* ar2 = (const float*)d_in[10];
  const float* b2  = (const float*)d_in[11];
  const float* Wc  = (const float*)d_in[12];
  const float* bc  = (const float*)d_in[13];
  float* out = (float*)d_out;

  char* wp = (char*)d_ws;
  auto carve = [&](size_t bytes) -> void* {
    void* p = (void*)wp;
    wp += (bytes + 255) & ~(size_t)255;
    return p;
  };
  unsigned char* fs = (unsigned char*)carve((size_t)MPAD * FDIM);        // 12.8 MB fp8
  unsigned short* h1 = (unsigned short*)carve((size_t)MPAD * FDIM * 2);  // 25.6 MB bf16
  unsigned short* h2 = h1;
  unsigned short* Wt1 = (unsigned short*)carve((size_t)256 * 128 * 2);
  unsigned short* Wt2 = (unsigned short*)carve((size_t)256 * 256 * 2);
  float* el      = (float*)carve((size_t)MPAD * NHEAD * 4);
  float* er      = (float*)carve((size_t)MPAD * NHEAD * 4);
  int* rowstart  = (int*)  carve((size_t)(N_NODES + 1) * 4);
  int* esrc      = (int*)  carve((size_t)N_EDGES * 4);
  int* gstart    = (int*)  carve((size_t)(N_GRAPHS + 1) * 4);
  int* bsum      = (int*)  carve((size_t)SCAN_NB * 4);
  int* counts    = (int*)  carve((size_t)CNTN * 4);
  int* cbase     = (int*)  carve((size_t)CNTN * 4);
  int2* ebuf     = (int2*) carve((size_t)N_EDGES * 8);                   // 4 MB
  float* ppart   = (float*)carve((size_t)N_GRAPHS * PSPLIT * FDIM * 4);  // 1 MB
  (void)ws_size; (void)n_in; (void)in_sizes; (void)out_size;

  // CSR build + weight prep (10 dispatches total, no memsets, no global atomics)
  cast_hist_kernel<<<NB1 + CAST_NB, 256, 0, stream>>>(
      W1, W2, Wt1, Wt2, n2g, gstart, dst, counts, rowstart);
  scan_local_kernel<<<SCAN_NB, 256, 0, stream>>>(counts, cbase, bsum, CNTN);
  bucket_scatter_kernel<<<NB1, 256, 0, stream>>>(src, dst, cbase, bsum, ebuf);
  csr_bucket_kernel<<<NBKT, 256, 0, stream>>>(ebuf, cbase, bsum, rowstart, esrc);

  // layer 1
  gemm_mfma<128, true><<<MPAD / 64, 256, 0, stream>>>(
      (const void*)feat, Wt1, fs, al1, ar1, el, er, N_NODES);
  edge_agg_kernel<true><<<(N_NODES + 15) / 16, 256, 0, stream>>>(
      rowstart, esrc, el, er, fs, b1, h1, N_NODES);

  // layer 2
  gemm_mfma<256, false><<<MPAD / 64, 256, 0, stream>>>(
      (const void*)h1, Wt2, fs, al2, ar2, el, er, N_NODES);
  edge_agg_kernel<false><<<(N_NODES + 15) / 16, 256, 0, stream>>>(
      rowstart, esrc, el, er, fs, b2, h2, N_NODES);

  // readout
  pool_partial_kernel<<<N_GRAPHS * PSPLIT, 256, 0, stream>>>(h2, gstart, ppart);
  pool_cls_kernel<<<N_GRAPHS, 256, 0, stream>>>(ppart, gstart, Wc, bc, out);
}

// Round 5
// 214.288 us; speedup vs baseline: 1.1888x; 1.1888x over previous
//
#include <hip/hip_runtime.h>
#include <hip/hip_bf16.h>

#define N_NODES 50000
#define N_EDGES 500000
#define N_GRAPHS 64
#define FDIM 256   // H*HID
#define NHEAD 8
#define NC 10
#define SLOPE 0.2f
#define MPAD 50048  // N_NODES rounded up to 64
#define NBKT 196              // ceil(N_NODES/256) coarse buckets (dst>>8)
#define CNTN (NBKT * 256)     // 50176 = per-(bucket,block) count matrix
#define SCAN_NB (CNTN / 1024) // 49 scan blocks of 1024 (exact)
#define NB1 256               // pass-1 bucketing blocks
#define EPB 1956              // edges per pass-1 block (mult of 4; 256*1956 >= E)
#define LDSW 40               // LDS row stride in shorts: 80B -> <=2-way bank conflict
#define PSPLIT 16             // pool: slices per graph (64*16 = 1024 blocks)
#define CAST_THREADS (256*128 + 256*256 + N_NODES)   // 148304
#define CAST_NB ((CAST_THREADS + 255) / 256)         // 580

typedef __attribute__((ext_vector_type(8))) short bf16x8;
typedef __attribute__((ext_vector_type(4))) float f32x4;
typedef __attribute__((ext_vector_type(2))) float f32x2;
typedef __attribute__((ext_vector_type(4))) unsigned u32x4;

__device__ __forceinline__ unsigned short f2bf(float f) {
  unsigned x = __float_as_uint(f);
  x += 0x7fff + ((x >> 16) & 1);   // RNE
  return (unsigned short)(x >> 16);
}
__device__ __forceinline__ float b2f(unsigned short u) {
  return __uint_as_float((unsigned)u << 16);
}
// XOR swizzle for the gemm epilogue LDS stage (bijective per 256B row, keeps 16B blocks)
__device__ __forceinline__ int fswz(int node, int off) {
  return off ^ ((node & 7) << 5) ^ (((node >> 3) & 1) << 4);
}

// ---------------- fused: weight transposes + gstart + coarse dst histogram ----------------
__global__ void cast_hist_kernel(const float* __restrict__ W1, const float* __restrict__ W2,
                                 unsigned short* __restrict__ Wt1, unsigned short* __restrict__ Wt2,
                                 const int* __restrict__ n2g, int* __restrict__ gstart,
                                 const int* __restrict__ dst, int* __restrict__ counts,
                                 int* __restrict__ rowstart) {
  int t = threadIdx.x;
  if (blockIdx.x < NB1) {
    __shared__ int hist[NBKT];
    int b = blockIdx.x;
    if (t < NBKT) hist[t] = 0;
    __syncthreads();
    int start = b * EPB;
    int end = min(start + EPB, N_EDGES);
    for (int base = start + t * 4; base < end; base += 1024) {
      if (base + 3 < end) {
        int4 d = *(const int4*)(dst + base);
        atomicAdd(&hist[d.x >> 8], 1); atomicAdd(&hist[d.y >> 8], 1);
        atomicAdd(&hist[d.z >> 8], 1); atomicAdd(&hist[d.w >> 8], 1);
      } else {
        for (int e2 = base; e2 < end; ++e2) atomicAdd(&hist[dst[e2] >> 8], 1);
      }
    }
    __syncthreads();
    if (t < NBKT) counts[t * NB1 + b] = hist[t];
    return;
  }
  int e = (blockIdx.x - NB1) * 256 + t;
  if (e == 0) rowstart[N_NODES] = N_EDGES;
  if (e < 256 * 128) {
    int n = e / 128, k = e % 128;
    Wt1[(size_t)n * 128 + k] = f2bf(W1[(size_t)k * 256 + n]);
  } else if (e < 256 * 128 + 256 * 256) {
    int t2 = e - 256 * 128;
    int n = t2 / 256, k = t2 % 256;
    Wt2[(size_t)n * 256 + k] = f2bf(W2[(size_t)k * 256 + n]);
  } else {
    int i = e - (256 * 128 + 256 * 256);
    if (i < N_NODES) {
      int g1 = n2g[i];
      int g0 = (i == 0) ? -1 : n2g[i - 1];
      for (int g = g0 + 1; g <= g1; ++g) gstart[g] = i;
      if (i == N_NODES - 1) {
        for (int g = g1 + 1; g <= N_GRAPHS; ++g) gstart[g] = N_NODES;
      }
    }
  }
}

// ---- local exclusive scan of counts[0..CNTN) -> cbase (block-local) + bsum ----
__global__ void scan_local_kernel(const int* __restrict__ deg, int* __restrict__ outv,
                                  int* __restrict__ bsum, int n) {
  __shared__ int ws[4];
  int t = threadIdx.x, lane = t & 63, w = t >> 6;
  int base = blockIdx.x * 1024 + t * 4;
  int4 v = make_int4(0, 0, 0, 0);
  if (base + 3 < n) {
    v = *(const int4*)(deg + base);
  } else {
    if (base + 0 < n) v.x = deg[base + 0];
    if (base + 1 < n) v.y = deg[base + 1];
    if (base + 2 < n) v.z = deg[base + 2];
    if (base + 3 < n) v.w = deg[base + 3];
  }
  int s = v.x + v.y + v.z + v.w;
  int x = s;
  #pragma unroll
  for (int off = 1; off < 64; off <<= 1) {
    int y = __shfl_up(x, off);
    if (lane >= off) x += y;
  }
  if (lane == 63) ws[w] = x;
  __syncthreads();
  int woff = 0;
  #pragma unroll
  for (int i = 0; i < 4; ++i) woff += (i < w) ? ws[i] : 0;
  int excl = woff + x - s;
  int4 o;
  o.x = excl;
  o.y = excl + v.x;
  o.z = excl + v.x + v.y;
  o.w = excl + v.x + v.y + v.z;
  if (base + 3 < n) {
    *(int4*)(outv + base) = o;
  } else {
    if (base + 0 < n) outv[base + 0] = o.x;
    if (base + 1 < n) outv[base + 1] = o.y;
    if (base + 2 < n) outv[base + 2] = o.z;
    if (base + 3 < n) outv[base + 3] = o.w;
  }
  if (t == 255) bsum[blockIdx.x] = woff + x;
}

// Pass 1b: rank-scatter (src,dst) into bucket-major ebuf via absolute LDS cursors.
__global__ void bucket_scatter_kernel(const int* __restrict__ src, const int* __restrict__ dst,
                                      const int* __restrict__ cbase, const int* __restrict__ bsum,
                                      int2* __restrict__ ebuf) {
  __shared__ int cur[NBKT];
  __shared__ int boffl[SCAN_NB];
  int t = threadIdx.x, b = blockIdx.x;
  if (t < 64) {
    int v = (t < SCAN_NB) ? bsum[t] : 0;
    int x = v;
    #pragma unroll
    for (int off = 1; off < 64; off <<= 1) {
      int y = __shfl_up(x, off);
      if (t >= off) x += y;
    }
    if (t < SCAN_NB) boffl[t] = x - v;
  }
  __syncthreads();
  if (t < NBKT) {
    int idx = t * NB1 + b;
    cur[t] = cbase[idx] + boffl[idx >> 10];
  }
  __syncthreads();
  int start = b * EPB;
  int end = min(start + EPB, N_EDGES);
  for (int base = start + t * 4; base < end; base += 1024) {
    if (base + 3 < end) {
      int4 s = *(const int4*)(src + base);
      int4 d = *(const int4*)(dst + base);
      int r;
      r = atomicAdd(&cur[d.x >> 8], 1); ebuf[r] = make_int2(s.x, d.x);
      r = atomicAdd(&cur[d.y >> 8], 1); ebuf[r] = make_int2(s.y, d.y);
      r = atomicAdd(&cur[d.z >> 8], 1); ebuf[r] = make_int2(s.z, d.z);
      r = atomicAdd(&cur[d.w >> 8], 1); ebuf[r] = make_int2(s.w, d.w);
    } else {
      for (int e2 = base; e2 < end; ++e2) {
        int dd = dst[e2];
        int r = atomicAdd(&cur[dd >> 8], 1);
        ebuf[r] = make_int2(src[e2], dd);
      }
    }
  }
}

// Pass 2: one block per coarse bucket -> final rowstart + esrc, all in LDS.
__global__ void csr_bucket_kernel(const int2* __restrict__ ebuf, const int* __restrict__ cbase,
                                  const int* __restrict__ bsum,
                                  int* __restrict__ rowstart, int* __restrict__ esrc) {
  __shared__ int hist[256];
  __shared__ int cur[256];
  __shared__ int ws[4];
  __shared__ int boffl[SCAN_NB];
  int t = threadIdx.x;
  int bkt = blockIdx.x;
  hist[t] = 0;
  if (t >= 64 && t < 128) {
    int tt = t - 64;
    int v = (tt < SCAN_NB) ? bsum[tt] : 0;
    int x = v;
    #pragma unroll
    for (int off = 1; off < 64; off <<= 1) {
      int y = __shfl_up(x, off);
      if (tt >= off) x += y;
    }
    if (tt < SCAN_NB) boffl[tt] = x - v;
  }
  __syncthreads();
  int i0 = bkt * NB1;
  int segstart = cbase[i0] + boffl[i0 >> 10];
  int segend = N_EDGES;
  if (bkt + 1 < NBKT) {
    int i1 = (bkt + 1) * NB1;
    segend = cbase[i1] + boffl[i1 >> 10];
  }
  for (int e = segstart + t; e < segend; e += 256)
    atomicAdd(&hist[ebuf[e].y & 255], 1);
  __syncthreads();
  int lane = t & 63, w = t >> 6;
  int v = hist[t], x = v;
  #pragma unroll
  for (int off = 1; off < 64; off <<= 1) {
    int y = __shfl_up(x, off);
    if (lane >= off) x += y;
  }
  if (lane == 63) ws[w] = x;
  __syncthreads();
  int woff = 0;
  #pragma unroll
  for (int i = 0; i < 4; ++i) woff += (i < w) ? ws[i] : 0;
  int excl = woff + x - v;
  cur[t] = excl;
  int node = bkt * 256 + t;
  if (node < N_NODES) rowstart[node] = segstart + excl;
  __syncthreads();
  for (int e = segstart + t; e < segend; e += 256) {
    int2 p = ebuf[e];
    int r = atomicAdd(&cur[p.y & 255], 1);
    esrc[segstart + r] = p.x;
  }
}

// ---------------- LDS-staged MFMA GEMM + fused attention logits ----------------
template<int K, bool AF32>
__global__ void gemm_mfma(const void* __restrict__ Avoid,
                          const unsigned short* __restrict__ Wt,
                          unsigned char* __restrict__ fs,
                          const float* __restrict__ al, const float* __restrict__ ar,
                          float* __restrict__ el, float* __restrict__ er, int nrows) {
  constexpr int KC = K / 32;
  __shared__ __align__(16) unsigned short LDSbuf[(64 + 256) * LDSW];   // 25.6 KB
  unsigned short* Albs = LDSbuf;
  unsigned short* Wlds = LDSbuf + 64 * LDSW;
  const float* Af = (const float*)Avoid;
  const unsigned short* Ab = (const unsigned short*)Avoid;
  int t = threadIdx.x;
  int lane = t & 63;
  int w = t >> 6;
  int row0 = blockIdx.x * 64;
  int m = lane & 15;
  int q = lane >> 4;
  float4 a32[2];
  bf16x8 a16;
  bf16x8 wtr[4];
  int arow = t >> 2, apiece = t & 3;
  int agrow = min(row0 + arow, nrows - 1);
  int frow0 = t >> 3, fquad0 = t & 7;
  int frow1 = (256 + t) >> 3, fquad1 = t & 7;
  int fgrow0 = min(row0 + frow0, nrows - 1);
  int fgrow1 = min(row0 + frow1, nrows - 1);

  auto stage = [&](int kc) {
    if (AF32) {
      a32[0] = *(const float4*)(Af + (size_t)fgrow0 * K + kc * 32 + fquad0 * 4);
      a32[1] = *(const float4*)(Af + (size_t)fgrow1 * K + kc * 32 + fquad1 * 4);
    } else {
      a16 = *(const bf16x8*)(Ab + (size_t)agrow * K + kc * 32 + apiece * 8);
    }
    #pragma unroll
    for (int j = 0; j < 4; ++j) {
      int row = j * 64 + (t >> 2);
      wtr[j] = *(const bf16x8*)(Wt + (size_t)row * K + kc * 32 + (t & 3) * 8);
    }
  };
  auto commit = [&]() {
    if (AF32) {
      ushort4 o0, o1;
      o0.x = f2bf(a32[0].x); o0.y = f2bf(a32[0].y); o0.z = f2bf(a32[0].z); o0.w = f2bf(a32[0].w);
      o1.x = f2bf(a32[1].x); o1.y = f2bf(a32[1].y); o1.z = f2bf(a32[1].z); o1.w = f2bf(a32[1].w);
      *(ushort4*)(Albs + frow0 * LDSW + fquad0 * 4) = o0;
      *(ushort4*)(Albs + frow1 * LDSW + fquad1 * 4) = o1;
    } else {
      *(bf16x8*)(Albs + arow * LDSW + apiece * 8) = a16;
    }
    #pragma unroll
    for (int j = 0; j < 4; ++j) {
      int row = j * 64 + (t >> 2);
      *(bf16x8*)(Wlds + row * LDSW + (t & 3) * 8) = wtr[j];
    }
  };

  f32x4 acc[16];
  #pragma unroll
  for (int nt = 0; nt < 16; ++nt) acc[nt] = (f32x4){0.f, 0.f, 0.f, 0.f};

  stage(0);
  commit();
  for (int kc = 0; kc < KC; ++kc) {
    __syncthreads();
    if (kc + 1 < KC) stage(kc + 1);
    bf16x8 af = *(const bf16x8*)(Albs + (w * 16 + m) * LDSW + q * 8);
    #pragma unroll
    for (int nt = 0; nt < 16; ++nt) {
      bf16x8 bfv = *(const bf16x8*)(Wlds + (nt * 16 + m) * LDSW + q * 8);
      acc[nt] = __builtin_amdgcn_mfma_f32_16x16x32_bf16(bfv, af, acc[nt], 0, 0, 0);
    }
    __syncthreads();
    if (kc + 1 < KC) commit();
  }
  // LDSbuf dead after the final barrier -> reuse for the coalescing epilogue.
  unsigned char* fsst = (unsigned char*)LDSbuf;          // 16384 B
  float* elst = (float*)(fsst + 16384);                  // 2048 B
  float* erst = elst + 512;                              // 2048 B

  int nloc = w * 16 + m;
  float elh[NHEAD], erh[NHEAD];
  #pragma unroll
  for (int h = 0; h < NHEAD; ++h) { elh[h] = 0.f; erh[h] = 0.f; }
  #pragma unroll
  for (int nt = 0; nt < 16; ++nt) {
    int h = nt >> 1;
    int c0 = (nt & 1) * 16 + q * 4;
    float4 a4 = *(const float4*)(al + h * 32 + c0);
    float4 r4 = *(const float4*)(ar + h * 32 + c0);
    elh[h] += acc[nt][0] * a4.x + acc[nt][1] * a4.y + acc[nt][2] * a4.z + acc[nt][3] * a4.w;
    erh[h] += acc[nt][0] * r4.x + acc[nt][1] * r4.y + acc[nt][2] * r4.z + acc[nt][3] * r4.w;
  }
  #pragma unroll
  for (int h = 0; h < NHEAD; ++h) {
    elh[h] += __shfl_xor(elh[h], 16); elh[h] += __shfl_xor(elh[h], 32);
    erh[h] += __shfl_xor(erh[h], 16); erh[h] += __shfl_xor(erh[h], 32);
  }
  #pragma unroll
  for (int nt = 0; nt < 16; ++nt) {
    int pk = 0;
    pk = __builtin_amdgcn_cvt_pk_fp8_f32(acc[nt][0], acc[nt][1], pk, false);
    pk = __builtin_amdgcn_cvt_pk_fp8_f32(acc[nt][2], acc[nt][3], pk, true);
    *(unsigned*)(fsst + nloc * 256 + fswz(nloc, nt * 16 + q * 4)) = (unsigned)pk;
  }
  *(float2*)(elst + nloc * 8 + q * 2) = make_float2(elh[2 * q], elh[2 * q + 1]);
  *(float2*)(erst + nloc * 8 + q * 2) = make_float2(erh[2 * q], erh[2 * q + 1]);
  __syncthreads();
  #pragma unroll
  for (int i = 0; i < 4; ++i) {
    int p = i * 4096 + t * 16;
    int nn = p >> 8, off = p & 255;
    u32x4 d = *(const u32x4*)(fsst + nn * 256 + fswz(nn, off));
    *(u32x4*)(fs + (size_t)row0 * 256 + p) = d;
  }
  if (t < 128) {
    *(float4*)(el + (size_t)row0 * 8 + t * 4) = *(const float4*)(elst + t * 4);
  } else {
    int tt = t - 128;
    *(float4*)(er + (size_t)row0 * 8 + tt * 4) = *(const float4*)(erst + tt * 4);
  }
}

// ---------------- fused edge softmax + aggregation: one wave per dst node ----------------
// Reverted to wave-per-node (max TLP: 50K waves — in-wave pipelining regressed, r4).
// Hot path: full groups of 8 edges with NO index clamps; single clamped tail group.
template<bool RELU>
__global__ __launch_bounds__(256, 8)
void edge_agg_kernel(const int* __restrict__ rowstart, const int* __restrict__ esrc,
                     const float* __restrict__ el, const float* __restrict__ er,
                     const unsigned char* __restrict__ fs,
                     const float* __restrict__ bias,
                     unsigned short* __restrict__ out, int nnodes) {
  int gid = blockIdx.x * blockDim.x + threadIdx.x;
  int v = gid >> 6;
  int lane = threadIdx.x & 63;
  if (v >= nnodes) return;
  int h = lane >> 3;       // consumer head
  int t8 = lane >> 3;      // producer edge slot
  int hh = lane & 7;       // producer head
  int row0 = rowstart[v];
  int deg = rowstart[v + 1] - row0;
  float er_w = er[v * NHEAD + hh];
  const unsigned char* fsl = fs + lane * 4;   // 4 fp8 bytes per lane
  const float* elp = el;
  float4 acc0 = make_float4(0.f, 0.f, 0.f, 0.f);
  float4 acc1 = make_float4(0.f, 0.f, 0.f, 0.f);
  float ws0 = 0.f, ws1 = 0.f;

  for (int base = 0; base < deg; base += 64) {
    int mm = min(deg - base, 64);
    int es = esrc[row0 + base + min(lane, mm - 1)];
    int full = mm & ~7;
    // ---- full groups: no clamps anywhere ----
    for (int j0 = 0; j0 < full; j0 += 8) {
      int sj = __shfl(es, j0 + t8);
      float x = elp[(unsigned)sj * 8u + hh] + er_w;
      x = fmaxf(x, SLOPE * x);
      float wp = __expf(x);
      float wt[8]; unsigned f[8];
      #pragma unroll
      for (int t = 0; t < 8; ++t) {
        int s = __shfl(es, j0 + t);
        f[t] = *(const unsigned*)(fsl + ((unsigned)s << 8));
      }
      #pragma unroll
      for (int t = 0; t < 8; ++t) wt[t] = __shfl(wp, t * 8 + h);
      #pragma unroll
      for (int t = 0; t < 8; ++t) {
        float wgt = wt[t];
        f32x2 lo = __builtin_amdgcn_cvt_pk_f32_fp8(f[t], false);
        f32x2 hi = __builtin_amdgcn_cvt_pk_f32_fp8(f[t], true);
        if (t & 1) {
          ws1 += wgt;
          acc1.x = fmaf(wgt, lo.x, acc1.x);
          acc1.y = fmaf(wgt, lo.y, acc1.y);
          acc1.z = fmaf(wgt, hi.x, acc1.z);
          acc1.w = fmaf(wgt, hi.y, acc1.w);
        } else {
          ws0 += wgt;
          acc0.x = fmaf(wgt, lo.x, acc0.x);
          acc0.y = fmaf(wgt, lo.y, acc0.y);
          acc0.z = fmaf(wgt, hi.x, acc0.z);
          acc0.w = fmaf(wgt, hi.y, acc0.w);
        }
      }
    }
    // ---- tail group (1..7 edges): clamped, weights zeroed ----
    if (full < mm) {
      int sj = __shfl(es, min(full + t8, mm - 1));
      float x = elp[(unsigned)sj * 8u + hh] + er_w;
      x = fmaxf(x, SLOPE * x);
      float wp = __expf(x);
      if (full + t8 >= mm) wp = 0.f;
      float wt[8]; unsigned f[8];
      #pragma unroll
      for (int t = 0; t < 8; ++t) {
        int s = __shfl(es, min(full + t, mm - 1));
        f[t] = *(const unsigned*)(fsl + ((unsigned)s << 8));
      }
      #pragma unroll
      for (int t = 0; t < 8; ++t) wt[t] = __shfl(wp, t * 8 + h);
      #pragma unroll
      for (int t = 0; t < 8; ++t) {
        float wgt = wt[t];
        f32x2 lo = __builtin_amdgcn_cvt_pk_f32_fp8(f[t], false);
        f32x2 hi = __builtin_amdgcn_cvt_pk_f32_fp8(f[t], true);
        if (t & 1) {
          ws1 += wgt;
          acc1.x = fmaf(wgt, lo.x, acc1.x);
          acc1.y = fmaf(wgt, lo.y, acc1.y);
          acc1.z = fmaf(wgt, hi.x, acc1.z);
          acc1.w = fmaf(wgt, hi.y, acc1.w);
        } else {
          ws0 += wgt;
          acc0.x = fmaf(wgt, lo.x, acc0.x);
          acc0.y = fmaf(wgt, lo.y, acc0.y);
          acc0.z = fmaf(wgt, hi.x, acc0.z);
          acc0.w = fmaf(wgt, hi.y, acc0.w);
        }
      }
    }
  }
  float wsum = ws0 + ws1;
  float4 acc;
  acc.x = acc0.x + acc1.x; acc.y = acc0.y + acc1.y;
  acc.z = acc0.z + acc1.z; acc.w = acc0.w + acc1.w;
  float rdenom = (deg > 0) ? (1.0f / wsum) : 0.f;
  const float4 b = *(const float4*)(bias + lane * 4);
  acc.x = fmaf(acc.x, rdenom, b.x);
  acc.y = fmaf(acc.y, rdenom, b.y);
  acc.z = fmaf(acc.z, rdenom, b.z);
  acc.w = fmaf(acc.w, rdenom, b.w);
  if (RELU) {
    acc.x = fmaxf(acc.x, 0.f); acc.y = fmaxf(acc.y, 0.f);
    acc.z = fmaxf(acc.z, 0.f); acc.w = fmaxf(acc.w, 0.f);
  }
  ushort4 o;
  o.x = f2bf(acc.x); o.y = f2bf(acc.y); o.z = f2bf(acc.z); o.w = f2bf(acc.w);
  *(ushort4*)(out + (size_t)v * FDIM + lane * 4) = o;
}

// ---------------- pool: split-K partials (1024 blocks), zero atomics ----------------
__global__ void pool_partial_kernel(const unsigned short* __restrict__ h2,
                                    const int* __restrict__ gstart,
                                    float* __restrict__ ppart) {
  int t = threadIdx.x;   // channel
  int g = blockIdx.x / PSPLIT;
  int s = blockIdx.x % PSPLIT;
  int n0 = gstart[g], n1 = gstart[g + 1];
  int cnt = n1 - n0;
  int chunk = (cnt + PSPLIT - 1) / PSPLIT;
  int a = n0 + s * chunk;
  int bnd = min(a + chunk, n1);
  float s0 = 0.f, s1 = 0.f, s2 = 0.f, s3 = 0.f;
  int n = a;
  for (; n + 4 <= bnd; n += 4) {
    s0 += b2f(h2[(size_t)(n + 0) * FDIM + t]);
    s1 += b2f(h2[(size_t)(n + 1) * FDIM + t]);
    s2 += b2f(h2[(size_t)(n + 2) * FDIM + t]);
    s3 += b2f(h2[(size_t)(n + 3) * FDIM + t]);
  }
  for (; n < bnd; ++n) s0 += b2f(h2[(size_t)n * FDIM + t]);
  ppart[(size_t)blockIdx.x * FDIM + t] = (s0 + s1) + (s2 + s3);
}

// ---------------- fused pool-reduce + classifier: one block per graph ----------------
__global__ void pool_cls_kernel(const float* __restrict__ ppart, const int* __restrict__ gstart,
                                const float* __restrict__ Wc, const float* __restrict__ bcv,
                                float* __restrict__ out) {
  __shared__ float hgl[FDIM];
  int t = threadIdx.x, g = blockIdx.x;
  float s = 0.f;
  #pragma unroll
  for (int sp = 0; sp < PSPLIT; ++sp)
    s += ppart[(size_t)(g * PSPLIT + sp) * FDIM + t];
  hgl[t] = s;
  __syncthreads();
  int cnt = gstart[g + 1] - gstart[g];
  float inv = (cnt > 0) ? (1.0f / (float)cnt) : 1.0f;
  int w = t >> 6, lane = t & 63;
  for (int j = w; j < NC; j += 4) {
    float p = 0.f;
    #pragma unroll
    for (int k = 0; k < 4; ++k) {
      int c = lane * 4 + k;
      p += hgl[c] * Wc[c * NC + j];
    }
    #pragma unroll
    for (int off = 1; off < 64; off <<= 1) p += __shfl_xor(p, off);
    if (lane == 0) out[g * NC + j] = p * inv + bcv[j];
  }
}

extern "C" void kernel_launch(void* const* d_in, const int* in_sizes, int n_in,
                              void* d_out, int out_size, void* d_ws, size_t ws_size,
                              hipStream_t stream) {
  const float* feat = (const float*)d_in[0];
  const int* src    = (const int*)d_in[1];
  const int* dst    = (const int*)d_in[2];
  const int* n2g    = (const int*)d_in[3];
  const float* W1  = (const float*)d_in[4];
  const float* al1 = (const float*)d_in[5];
  const float* ar1 = (const float*)d_in[6];
  const float* b1  = (const float*)d_in[7];
  const float* W2  = (const float*)d_in[8];
  const float* al2 = (const float*)d_in[9];
  const float* ar2 = (const float*)d_in[10];
  const float* b2  = (const float*)d_in[11];
  const float* Wc  = (const float*)d_in[12];
  const float* bc  = (const float*)d_in[13];
  float* out = (float*)d_out;

  char* wp = (char*)d_ws;
  auto carve = [&](size_t bytes) -> void* {
    void* p = (void*)wp;
    wp += (bytes + 255) & ~(size_t)255;
    return p;
  };
  unsigned char* fs = (unsigned char*)carve((size_t)MPAD * FDIM);        // 12.8 MB fp8
  unsigned short* h1 = (unsigned short*)carve((size_t)MPAD * FDIM * 2);  // 25.6 MB bf16
  unsigned short* h2 = h1;
  unsigned short* Wt1 = (unsigned short*)carve((size_t)256 * 128 * 2);
  unsigned short* Wt2 = (unsigned short*)carve((size_t)256 * 256 * 2);
  float* el      = (float*)carve((size_t)MPAD * NHEAD * 4);
  float* er      = (float*)carve((size_t)MPAD * NHEAD * 4);
  int* rowstart  = (int*)  carve((size_t)(N_NODES + 1) * 4);
  int* esrc      = (int*)  carve((size_t)N_EDGES * 4);
  int* gstart    = (int*)  carve((size_t)(N_GRAPHS + 1) * 4);
  int* bsum      = (int*)  carve((size_t)SCAN_NB * 4);
  int* counts    = (int*)  carve((size_t)CNTN * 4);
  int* cbase     = (int*)  carve((size_t)CNTN * 4);
  int2* ebuf     = (int2*) carve((size_t)N_EDGES * 8);                   // 4 MB
  float* ppart   = (float*)carve((size_t)N_GRAPHS * PSPLIT * FDIM * 4);  // 1 MB
  (void)ws_size; (void)n_in; (void)in_sizes; (void)out_size;

  // CSR build + weight prep (no memsets, no global atomics)
  cast_hist_kernel<<<NB1 + CAST_NB, 256, 0, stream>>>(
      W1, W2, Wt1, Wt2, n2g, gstart, dst, counts, rowstart);
  scan_local_kernel<<<SCAN_NB, 256, 0, stream>>>(counts, cbase, bsum, CNTN);
  bucket_scatter_kernel<<<NB1, 256, 0, stream>>>(src, dst, cbase, bsum, ebuf);
  csr_bucket_kernel<<<NBKT, 256, 0, stream>>>(ebuf, cbase, bsum, rowstart, esrc);

  // layer 1
  gemm_mfma<128, true><<<MPAD / 64, 256, 0, stream>>>(
      (const void*)feat, Wt1, fs, al1, ar1, el, er, N_NODES);
  edge_agg_kernel<true><<<(N_NODES * 64 + 255) / 256, 256, 0, stream>>>(
      rowstart, esrc, el, er, fs, b1, h1, N_NODES);

  // layer 2
  gemm_mfma<256, false><<<MPAD / 64, 256, 0, stream>>>(
      (const void*)h1, Wt2, fs, al2, ar2, el, er, N_NODES);
  edge_agg_kernel<false><<<(N_NODES * 64 + 255) / 256, 256, 0, stream>>>(
      rowstart, esrc, el, er, fs, b2, h2, N_NODES);

  // readout
  pool_partial_kernel<<<N_GRAPHS * PSPLIT, 256, 0, stream>>>(h2, gstart, ppart);
  pool_cls_kernel<<<N_GRAPHS, 256, 0, stream>>>(ppart, gstart, Wc, bc, out);
}